// Round 2
// baseline (289.312 us; speedup 1.0000x reference)
//
#include <hip/hip_runtime.h>
#include <hip/hip_bf16.h>

#define IN_DIM   128
#define HIDDEN   128
#define KDIM     256          // 2*IN_DIM
#define BLOCK_E  128
#define NTHREADS 512
#define LDB      264          // padded LDS row length in bf16 (264*2 = 528 B = 33*16B)

typedef __attribute__((ext_vector_type(8))) short  bf16x8;
typedef __attribute__((ext_vector_type(4))) float  f32x4;

__device__ __forceinline__ unsigned short f2bf(float f) {
    union { __hip_bfloat16 h; unsigned short u; } cv;
    cv.h = __float2bfloat16(f);
    return cv.u;
}

// Pre-pass: W1 [256][128] f32 -> W1T [128][256] bf16 (K-contiguous rows for MFMA B frags)
__global__ void w1_transpose_bf16(const float* __restrict__ W1,
                                  unsigned short* __restrict__ W1T) {
    int o = blockIdx.x * blockDim.x + threadIdx.x;
    if (o >= HIDDEN * KDIM) return;
    int n = o >> 8;      // 0..127 (hidden)
    int k = o & 255;     // 0..255 (concat-K)
    W1T[o] = f2bf(W1[k * HIDDEN + n]);
}

__global__ __launch_bounds__(NTHREADS, 1)
void link_mlp_kernel(const float* __restrict__ pat,
                     const float* __restrict__ cond,
                     const int* __restrict__ eidx,     // int32! harness converts int64 -> int32
                     const unsigned short* __restrict__ W1T,
                     const float* __restrict__ b1,
                     const float* __restrict__ W2,
                     const float* __restrict__ b2,
                     float* __restrict__ out,
                     int E, int n_nodes)
{
    __shared__ unsigned short sA[BLOCK_E][LDB];   // gathered concat(src,dst) bf16
    __shared__ unsigned short sB[HIDDEN][LDB];    // W1T bf16
    __shared__ int   sh_idx[2 * BLOCK_E];
    __shared__ float sh_logit[BLOCK_E];

    const int t  = threadIdx.x;
    const int e0 = blockIdx.x * BLOCK_E;

    // ---- load edge indices (clamped for tail + fault insurance) ----
    if (t < 2 * BLOCK_E) {
        int i = t;
        int e = e0 + (i & (BLOCK_E - 1));
        int v = 0;
        if (e < E) v = (i < BLOCK_E) ? eidx[e] : eidx[E + e];
        v = min(max(v, 0), n_nodes - 1);
        sh_idx[i] = v;
    }
    if (t < BLOCK_E) sh_logit[t] = 0.f;
    __syncthreads();

    const int lane32 = t & 31;
    const int grp    = t >> 5;    // 0..15

    // ---- stage W1T into sB: 128 rows x 512B, one 32-lane group per row ----
    {
        const uint4* src = (const uint4*)W1T;     // 16 B = 8 bf16
        #pragma unroll
        for (int it = 0; it < 8; ++it) {
            int r = it * 16 + grp;
            uint4 v = src[r * 32 + lane32];
            *(uint4*)&sB[r][lane32 * 8] = v;
        }
    }
    // ---- gather + convert embeddings into sA ----
    {
        #pragma unroll
        for (int it = 0; it < 16; ++it) {
            int rh   = it * 16 + grp;          // 0..255 row-halves
            int half = rh >> 7;                // 0 = src(patient), 1 = dst(condition)
            int e    = rh & (BLOCK_E - 1);
            int node = sh_idx[half * BLOCK_E + e];
            const float4* srcp =
                (const float4*)((half ? cond : pat) + (long long)node * IN_DIM);
            float4 v = srcp[lane32];
            ushort4 hv;
            hv.x = f2bf(v.x); hv.y = f2bf(v.y); hv.z = f2bf(v.z); hv.w = f2bf(v.w);
            *(ushort4*)&sA[e][half * IN_DIM + lane32 * 4] = hv;
        }
    }
    __syncthreads();

    // ---- MFMA: [128 x 256] @ [256 x 128], waves 4(M) x 2(N) ----
    const int w    = t >> 6;        // 0..7
    const int lane = t & 63;
    const int wm   = w >> 1;        // 0..3 -> rows wm*32
    const int wn   = w & 1;         // 0..1 -> cols wn*64
    const int l15  = lane & 15;
    const int l4   = lane >> 4;     // 0..3

    f32x4 acc[2][4];
    #pragma unroll
    for (int mt = 0; mt < 2; ++mt)
        #pragma unroll
        for (int nt = 0; nt < 4; ++nt)
            acc[mt][nt] = (f32x4){0.f, 0.f, 0.f, 0.f};

    #pragma unroll
    for (int ks = 0; ks < 8; ++ks) {
        const int kof = ks * 32 + l4 * 8;
        bf16x8 a[2], b[4];
        #pragma unroll
        for (int mt = 0; mt < 2; ++mt)
            a[mt] = *(const bf16x8*)&sA[wm * 32 + mt * 16 + l15][kof];
        #pragma unroll
        for (int nt = 0; nt < 4; ++nt)
            b[nt] = *(const bf16x8*)&sB[wn * 64 + nt * 16 + l15][kof];
        #pragma unroll
        for (int mt = 0; mt < 2; ++mt)
            #pragma unroll
            for (int nt = 0; nt < 4; ++nt)
                acc[mt][nt] = __builtin_amdgcn_mfma_f32_16x16x32_bf16(
                    a[mt], b[nt], acc[mt][nt], 0, 0, 0);
    }

    // ---- layer 2: +b1, relu, dot W2, reduce over hidden dim ----
    float b1v[4], w2v[4];
    #pragma unroll
    for (int nt = 0; nt < 4; ++nt) {
        int n = wn * 64 + nt * 16 + l15;
        b1v[nt] = b1[n];
        w2v[nt] = W2[n];
    }
    #pragma unroll
    for (int mt = 0; mt < 2; ++mt) {
        float part[4];
        #pragma unroll
        for (int r = 0; r < 4; ++r) {
            float p = 0.f;
            #pragma unroll
            for (int nt = 0; nt < 4; ++nt) {
                float h = acc[mt][nt][r] + b1v[nt];
                h = fmaxf(h, 0.f);
                p += h * w2v[nt];
            }
            part[r] = p;
        }
        // reduce across the 16 columns held by lanes sharing l4
        #pragma unroll
        for (int off = 1; off < 16; off <<= 1)
            #pragma unroll
            for (int r = 0; r < 4; ++r)
                part[r] += __shfl_xor(part[r], off, 64);
        if (l15 == 0) {
            int rowb = wm * 32 + mt * 16 + l4 * 4;
            #pragma unroll
            for (int r = 0; r < 4; ++r)
                atomicAdd(&sh_logit[rowb + r], part[r]);
        }
    }
    __syncthreads();

    // ---- sigmoid + store ----
    if (t < BLOCK_E) {
        int e = e0 + t;
        if (e < E) {
            float x = sh_logit[t] + b2[0];
            out[e] = 1.f / (1.f + __expf(-x));
        }
    }
}

extern "C" void kernel_launch(void* const* d_in, const int* in_sizes, int n_in,
                              void* d_out, int out_size, void* d_ws, size_t ws_size,
                              hipStream_t stream) {
    const float* pat  = (const float*)d_in[0];
    const float* cond = (const float*)d_in[1];
    const int*   eidx = (const int*)d_in[2];     // int64 in reference -> int32 on device
    const float* W1   = (const float*)d_in[3];
    const float* b1   = (const float*)d_in[4];
    const float* W2   = (const float*)d_in[5];
    const float* b2   = (const float*)d_in[6];
    float*       out  = (float*)d_out;

    const int E       = in_sizes[2] / 2;
    const int n_nodes = in_sizes[0] / IN_DIM;
    unsigned short* W1T = (unsigned short*)d_ws;   // 128*256*2 = 64 KB scratch

    w1_transpose_bf16<<<(HIDDEN * KDIM + 255) / 256, 256, 0, stream>>>(W1, W1T);

    const int nblocks = (E + BLOCK_E - 1) / BLOCK_E;
    link_mlp_kernel<<<nblocks, NTHREADS, 0, stream>>>(
        pat, cond, eidx, W1T, b1, W2, b2, out, E, n_nodes);
}